// Round 1
// baseline (323.796 us; speedup 1.0000x reference)
//
#include <hip/hip_runtime.h>

// N=4096 tokens, D=1024. All GEMMs NT-form (both operands row-major with K fast)
// via mfma_f32_16x16x32_bf16, fp32 accumulate.
//
// ws layout (needs 64 MB):
//   Qb  bf16 [4096,1024]  @ 0
//   Kb  bf16 [4096,1024]  @ 8MB
//   Vb  bf16 [4096,1024]  @ 16MB
//   Vt  bf16 [1024,4096]  @ 24MB
//   SP  bf16 [4096,4096]  @ 32MB   (scores, then softmax'd in place)

#define N_TOK 4096
#define DDIM  1024

typedef short s16x8 __attribute__((ext_vector_type(8)));
typedef float f32x4 __attribute__((ext_vector_type(4)));

__device__ inline short f2b(float f) {
  // round-to-nearest-even fp32 -> bf16 (no NaN in this problem)
  unsigned int u = __float_as_uint(f);
  unsigned int r = (u + 0x7FFFu + ((u >> 16) & 1u)) >> 16;
  return (short)(unsigned short)r;
}
__device__ inline float b2f(short s) {
  return __uint_as_float(((unsigned int)(unsigned short)s) << 16);
}

// ---------------------------------------------------------------------------
// Kernel 1: Q/K/V projection.  out_bf16[r,c] = bf16( sum_k x[r,k]*W[c,k] + b[c] )
// blockIdx.z selects (Wq,bq,Qb)/(Wk,bk,Kb)/(Wv,bv,Vb).
// Tile 128x128, BK=32. LDS row stride 40 bf16 (pad to dodge bank conflicts).
// ---------------------------------------------------------------------------
__global__ __launch_bounds__(256)
void gemm_qkv(const float* __restrict__ x,
              const float* __restrict__ Wq, const float* __restrict__ bq,
              const float* __restrict__ Wk, const float* __restrict__ bk,
              const float* __restrict__ Wv, const float* __restrict__ bv,
              short* __restrict__ Qb, short* __restrict__ Kb, short* __restrict__ Vb)
{
  const float* W; const float* bias; short* out;
  if (blockIdx.z == 0)      { W = Wq; bias = bq; out = Qb; }
  else if (blockIdx.z == 1) { W = Wk; bias = bk; out = Kb; }
  else                      { W = Wv; bias = bv; out = Vb; }

  __shared__ short As[128 * 40];
  __shared__ short Bs[128 * 40];

  const int tid  = threadIdx.x;
  const int row0 = blockIdx.y * 128;   // x rows
  const int col0 = blockIdx.x * 128;   // output cols = W rows

  const int sr = tid >> 1;             // staging row 0..127
  const int sc = (tid & 1) * 16;       // staging col 0 / 16

  const int wid  = tid >> 6;
  const int lane = tid & 63;
  const int wm = wid >> 1, wn = wid & 1;
  const int quad = lane >> 4, lr = lane & 15;

  f32x4 acc[4][4];
  #pragma unroll
  for (int i = 0; i < 4; i++)
    #pragma unroll
    for (int j = 0; j < 4; j++) acc[i][j] = {0.f, 0.f, 0.f, 0.f};

  for (int kk = 0; kk < DDIM; kk += 32) {
    __syncthreads();
    {
      const float4* ga = reinterpret_cast<const float4*>(x + (size_t)(row0 + sr) * DDIM + kk + sc);
      float4 f0 = ga[0], f1 = ga[1], f2 = ga[2], f3 = ga[3];
      float ff[16] = {f0.x,f0.y,f0.z,f0.w, f1.x,f1.y,f1.z,f1.w,
                      f2.x,f2.y,f2.z,f2.w, f3.x,f3.y,f3.z,f3.w};
      s16x8 t0, t1;
      #pragma unroll
      for (int i = 0; i < 8; i++) { t0[i] = f2b(ff[i]); t1[i] = f2b(ff[8 + i]); }
      *reinterpret_cast<s16x8*>(&As[sr * 40 + sc])     = t0;
      *reinterpret_cast<s16x8*>(&As[sr * 40 + sc + 8]) = t1;
    }
    {
      const float4* gb = reinterpret_cast<const float4*>(W + (size_t)(col0 + sr) * DDIM + kk + sc);
      float4 f0 = gb[0], f1 = gb[1], f2 = gb[2], f3 = gb[3];
      float ff[16] = {f0.x,f0.y,f0.z,f0.w, f1.x,f1.y,f1.z,f1.w,
                      f2.x,f2.y,f2.z,f2.w, f3.x,f3.y,f3.z,f3.w};
      s16x8 t0, t1;
      #pragma unroll
      for (int i = 0; i < 8; i++) { t0[i] = f2b(ff[i]); t1[i] = f2b(ff[8 + i]); }
      *reinterpret_cast<s16x8*>(&Bs[sr * 40 + sc])     = t0;
      *reinterpret_cast<s16x8*>(&Bs[sr * 40 + sc + 8]) = t1;
    }
    __syncthreads();

    s16x8 af[4], bfr[4];
    #pragma unroll
    for (int i = 0; i < 4; i++)
      af[i] = *reinterpret_cast<const s16x8*>(&As[(wm * 64 + i * 16 + lr) * 40 + quad * 8]);
    #pragma unroll
    for (int j = 0; j < 4; j++)
      bfr[j] = *reinterpret_cast<const s16x8*>(&Bs[(wn * 64 + j * 16 + lr) * 40 + quad * 8]);
    #pragma unroll
    for (int i = 0; i < 4; i++)
      #pragma unroll
      for (int j = 0; j < 4; j++)
        acc[i][j] = __builtin_amdgcn_mfma_f32_16x16x32_bf16(af[i], bfr[j], acc[i][j], 0, 0, 0);
  }

  float bv4[4];
  #pragma unroll
  for (int j = 0; j < 4; j++) bv4[j] = bias[col0 + wn * 64 + j * 16 + lr];

  #pragma unroll
  for (int i = 0; i < 4; i++) {
    const int r0 = row0 + wm * 64 + i * 16 + quad * 4;
    #pragma unroll
    for (int j = 0; j < 4; j++) {
      const int c = col0 + wn * 64 + j * 16 + lr;
      #pragma unroll
      for (int r = 0; r < 4; r++)
        out[(size_t)(r0 + r) * DDIM + c] = f2b(acc[i][j][r] + bv4[j]);
    }
  }
}

// ---------------------------------------------------------------------------
// Kernel 2: V [4096,1024] -> Vt [1024,4096] (bf16), 64x64 LDS tiles
// ---------------------------------------------------------------------------
__global__ __launch_bounds__(256)
void transpose_bf16(const short* __restrict__ in, short* __restrict__ out)
{
  __shared__ short t[64][65];
  const int j0 = blockIdx.x * 64;   // input col tile
  const int i0 = blockIdx.y * 64;   // input row tile
  const int tid = threadIdx.x;
  const int r = tid >> 2;           // 0..63
  const int c = (tid & 3) * 16;     // 0,16,32,48

  const s16x8* g = reinterpret_cast<const s16x8*>(in + (size_t)(i0 + r) * 1024 + j0 + c);
  s16x8 v0 = g[0], v1 = g[1];
  #pragma unroll
  for (int k = 0; k < 8; k++) { t[r][c + k] = v0[k]; t[r][c + 8 + k] = v1[k]; }
  __syncthreads();

  s16x8 w0, w1;
  #pragma unroll
  for (int k = 0; k < 8; k++) { w0[k] = t[c + k][r]; w1[k] = t[c + 8 + k][r]; }
  s16x8* go = reinterpret_cast<s16x8*>(out + (size_t)(j0 + r) * 4096 + i0 + c);
  go[0] = w0; go[1] = w1;
}

// ---------------------------------------------------------------------------
// Kernel 3/5: generic NT GEMM, bf16 inputs.
// C[M, ldc] = scale * A @ B^T ; A [M,K] row-major, B [ldc,K] row-major.
// out_bf16 ? store bf16 : store fp32.
// ---------------------------------------------------------------------------
__global__ __launch_bounds__(256)
void gemm_nt(const short* __restrict__ A, const short* __restrict__ B,
             void* __restrict__ C, int K, int ldc, float scale, int out_bf16)
{
  __shared__ short As[128 * 40];
  __shared__ short Bs[128 * 40];

  const int tid  = threadIdx.x;
  const int row0 = blockIdx.y * 128;
  const int col0 = blockIdx.x * 128;

  const int sr = tid >> 1;
  const int sc = (tid & 1) * 16;

  const int wid  = tid >> 6;
  const int lane = tid & 63;
  const int wm = wid >> 1, wn = wid & 1;
  const int quad = lane >> 4, lr = lane & 15;

  f32x4 acc[4][4];
  #pragma unroll
  for (int i = 0; i < 4; i++)
    #pragma unroll
    for (int j = 0; j < 4; j++) acc[i][j] = {0.f, 0.f, 0.f, 0.f};

  for (int kk = 0; kk < K; kk += 32) {
    __syncthreads();
    {
      const s16x8* ga = reinterpret_cast<const s16x8*>(A + (size_t)(row0 + sr) * K + kk + sc);
      s16x8 v0 = ga[0], v1 = ga[1];
      *reinterpret_cast<s16x8*>(&As[sr * 40 + sc])     = v0;
      *reinterpret_cast<s16x8*>(&As[sr * 40 + sc + 8]) = v1;
    }
    {
      const s16x8* gb = reinterpret_cast<const s16x8*>(B + (size_t)(col0 + sr) * K + kk + sc);
      s16x8 v0 = gb[0], v1 = gb[1];
      *reinterpret_cast<s16x8*>(&Bs[sr * 40 + sc])     = v0;
      *reinterpret_cast<s16x8*>(&Bs[sr * 40 + sc + 8]) = v1;
    }
    __syncthreads();

    s16x8 af[4], bfr[4];
    #pragma unroll
    for (int i = 0; i < 4; i++)
      af[i] = *reinterpret_cast<const s16x8*>(&As[(wm * 64 + i * 16 + lr) * 40 + quad * 8]);
    #pragma unroll
    for (int j = 0; j < 4; j++)
      bfr[j] = *reinterpret_cast<const s16x8*>(&Bs[(wn * 64 + j * 16 + lr) * 40 + quad * 8]);
    #pragma unroll
    for (int i = 0; i < 4; i++)
      #pragma unroll
      for (int j = 0; j < 4; j++)
        acc[i][j] = __builtin_amdgcn_mfma_f32_16x16x32_bf16(af[i], bfr[j], acc[i][j], 0, 0, 0);
  }

  #pragma unroll
  for (int i = 0; i < 4; i++) {
    const int r0 = row0 + wm * 64 + i * 16 + quad * 4;
    #pragma unroll
    for (int j = 0; j < 4; j++) {
      const int c = col0 + wn * 64 + j * 16 + lr;
      #pragma unroll
      for (int r = 0; r < 4; r++) {
        const float v = acc[i][j][r] * scale;
        if (out_bf16) ((short*)C)[(size_t)(r0 + r) * ldc + c] = f2b(v);
        else          ((float*)C)[(size_t)(r0 + r) * ldc + c] = v;
      }
    }
  }
}

// ---------------------------------------------------------------------------
// Kernel 4: in-place row softmax over bf16 [4096, 4096]
// ---------------------------------------------------------------------------
__global__ __launch_bounds__(256)
void softmax_rows(short* __restrict__ SP)
{
  const int row = blockIdx.x;
  short* p = SP + (size_t)row * 4096;
  const int tid = threadIdx.x;
  const int wid = tid >> 6, lane = tid & 63;

  float v[16];
  const s16x8* g = reinterpret_cast<const s16x8*>(p + tid * 16);
  s16x8 a0 = g[0], a1 = g[1];
  #pragma unroll
  for (int k = 0; k < 8; k++) { v[k] = b2f(a0[k]); v[8 + k] = b2f(a1[k]); }

  float m = -1e30f;
  #pragma unroll
  for (int k = 0; k < 16; k++) m = fmaxf(m, v[k]);
  #pragma unroll
  for (int off = 32; off > 0; off >>= 1) m = fmaxf(m, __shfl_xor(m, off, 64));

  __shared__ float redm[4], reds[4];
  if (lane == 0) redm[wid] = m;
  __syncthreads();
  m = fmaxf(fmaxf(redm[0], redm[1]), fmaxf(redm[2], redm[3]));

  float s = 0.f;
  #pragma unroll
  for (int k = 0; k < 16; k++) { v[k] = __expf(v[k] - m); s += v[k]; }
  #pragma unroll
  for (int off = 32; off > 0; off >>= 1) s += __shfl_xor(s, off, 64);
  if (lane == 0) reds[wid] = s;
  __syncthreads();
  s = reds[0] + reds[1] + reds[2] + reds[3];
  const float inv = 1.0f / s;

  s16x8 o0, o1;
  #pragma unroll
  for (int k = 0; k < 8; k++) { o0[k] = f2b(v[k] * inv); o1[k] = f2b(v[8 + k] * inv); }
  s16x8* go = reinterpret_cast<s16x8*>(p + tid * 16);
  go[0] = o0; go[1] = o1;
}

// ---------------------------------------------------------------------------
extern "C" void kernel_launch(void* const* d_in, const int* in_sizes, int n_in,
                              void* d_out, int out_size, void* d_ws, size_t ws_size,
                              hipStream_t stream)
{
  const float* x  = (const float*)d_in[0];
  const float* Wq = (const float*)d_in[1];
  const float* bq = (const float*)d_in[2];
  const float* Wk = (const float*)d_in[3];
  const float* bk = (const float*)d_in[4];
  const float* Wv = (const float*)d_in[5];
  const float* bv = (const float*)d_in[6];
  float* out = (float*)d_out;

  char* ws = (char*)d_ws;
  const size_t MB = 1024 * 1024;
  short* Qb = (short*)(ws + 0 * MB);
  short* Kb = (short*)(ws + 8 * MB);
  short* Vb = (short*)(ws + 16 * MB);
  short* Vt = (short*)(ws + 24 * MB);
  short* SP = (short*)(ws + 32 * MB);   // 32 MB

  dim3 b256(256);

  // Q/K/V = x @ W^T + b  (bf16 out)
  gemm_qkv<<<dim3(DDIM / 128, N_TOK / 128, 3), b256, 0, stream>>>(
      x, Wq, bq, Wk, bk, Wv, bv, Qb, Kb, Vb);

  // Vt = V^T
  transpose_bf16<<<dim3(DDIM / 64, N_TOK / 64), b256, 0, stream>>>(Vb, Vt);

  // S = Q @ K^T / 32  (bf16, in ws)
  gemm_nt<<<dim3(N_TOK / 128, N_TOK / 128), b256, 0, stream>>>(
      Qb, Kb, (void*)SP, DDIM, N_TOK, 0.03125f, 1);

  // P = softmax(S) in place
  softmax_rows<<<dim3(N_TOK), b256, 0, stream>>>(SP);

  // O = P @ Vt^T  (fp32 out)
  gemm_nt<<<dim3(DDIM / 128, N_TOK / 128), b256, 0, stream>>>(
      SP, Vt, (void*)out, N_TOK, DDIM, 1.0f, 0);
}

// Round 2
// 248.557 us; speedup vs baseline: 1.3027x; 1.3027x over previous
//
#include <hip/hip_runtime.h>

// N=4096, D=1024 self-attention, all GEMMs NT-form bf16 MFMA (16x16x32), fp32 acc.
// m97-style staging: global_load_lds dwordx4 + XOR-swizzled LDS chunk layout
// (chunk (row,q) stored at slot q ^ ((row>>1)&3)) so fragment ds_read_b128s are
// stride-1 across lanes (conflict-free) while staging stays 64B-coalesced.
//
// ws layout (64 MB):
//   Qb bf16[4096,1024] @ 0      Kb @ 8MB     Vb @ 16MB    Vt bf16[1024,4096] @ 24MB
//   SP bf16[4096,4096] @ 32MB   (scores -> softmax in place)
//   xb bf16[4096,1024] @ 32MB?  -- no: xb/Wb overlap SP's region (dead by then):
//   xb @ 32MB (8MB), Wqb @ 40MB, Wkb @ 42MB, Wvb @ 44MB  (all dead before SP written)

#define N_TOK 4096
#define DDIM  1024

typedef short s16x8 __attribute__((ext_vector_type(8)));
typedef float f32x4 __attribute__((ext_vector_type(4)));

__device__ inline short f2b(float f) {
  unsigned int u = __float_as_uint(f);
  unsigned int r = (u + 0x7FFFu + ((u >> 16) & 1u)) >> 16;
  return (short)(unsigned short)r;
}
__device__ inline float b2f(short s) {
  return __uint_as_float(((unsigned int)(unsigned short)s) << 16);
}

__device__ __forceinline__ void gld_lds16(const short* g, short* l) {
  __builtin_amdgcn_global_load_lds(
      (const __attribute__((address_space(1))) unsigned int*)g,
      (__attribute__((address_space(3))) unsigned int*)l, 16, 0, 0);
}

// ---------------------------------------------------------------------------
// Core NT GEMM tile: C[BM,BN] (+bias) = scale * A @ B^T, bf16 in, fp32 acc.
// 256 threads = 4 waves in 2x2; each wave (BM/2)x(BN/2) via 16x16x32 MFMA.
// ---------------------------------------------------------------------------
template<int BM, int BN, typename OutT, bool HAS_BIAS>
__device__ __forceinline__ void gemm_core(
    const short* __restrict__ A, const short* __restrict__ B,
    OutT* __restrict__ C, const float* __restrict__ bias,
    int K, int ldc, float scale, int row0, int col0)
{
  constexpr int WM = BM / 2, WN = BN / 2, AI = WM / 16, AJ = WN / 16;
  __shared__ short As[BM * 32];
  __shared__ short Bs[BN * 32];

  const int tid  = threadIdx.x;
  const int wave = tid >> 6, lane = tid & 63;
  const int wm = wave >> 1, wn = wave & 1;
  const int quad = lane >> 4, lr = lane & 15;
  const int slotx = quad ^ ((lr >> 1) & 3);   // fragment-read swizzle slot

  f32x4 acc[AI][AJ];
  #pragma unroll
  for (int i = 0; i < AI; i++)
    #pragma unroll
    for (int j = 0; j < AJ; j++) acc[i][j] = {0.f, 0.f, 0.f, 0.f};

  for (int kk = 0; kk < K; kk += 32) {
    __syncthreads();
    // A tile: BM rows x 32 bf16 = BM*4 16B-chunks; 256 chunks per call.
    #pragma unroll
    for (int c = 0; c < BM / 64; c++) {
      const int id = c * 256 + wave * 64 + lane;           // chunk id
      const int r = id >> 2, slot = id & 3;
      const int q = slot ^ ((r >> 1) & 3);                 // which 8-elem K-chunk
      gld_lds16(A + (size_t)(row0 + r) * K + kk + q * 8,
                &As[(c * 256 + wave * 64) * 8]);           // wave-uniform base
    }
    #pragma unroll
    for (int c = 0; c < BN / 64; c++) {
      const int id = c * 256 + wave * 64 + lane;
      const int r = id >> 2, slot = id & 3;
      const int q = slot ^ ((r >> 1) & 3);
      gld_lds16(B + (size_t)(col0 + r) * K + kk + q * 8,
                &Bs[(c * 256 + wave * 64) * 8]);
    }
    __syncthreads();   // compiler drains vmcnt(0) here -> LDS valid

    s16x8 af[AI], bf[AJ];
    #pragma unroll
    for (int i = 0; i < AI; i++) {
      const int row = wm * WM + i * 16 + lr;
      af[i] = *reinterpret_cast<const s16x8*>(&As[(row * 4 + slotx) * 8]);
    }
    #pragma unroll
    for (int j = 0; j < AJ; j++) {
      const int row = wn * WN + j * 16 + lr;
      bf[j] = *reinterpret_cast<const s16x8*>(&Bs[(row * 4 + slotx) * 8]);
    }
    #pragma unroll
    for (int i = 0; i < AI; i++)
      #pragma unroll
      for (int j = 0; j < AJ; j++)
        acc[i][j] = __builtin_amdgcn_mfma_f32_16x16x32_bf16(af[i], bf[j], acc[i][j], 0, 0, 0);
  }

  float bb[AJ];
  if (HAS_BIAS) {
    #pragma unroll
    for (int j = 0; j < AJ; j++) bb[j] = bias[col0 + wn * WN + j * 16 + lr];
  }

  #pragma unroll
  for (int i = 0; i < AI; i++) {
    const int r0 = row0 + wm * WM + i * 16 + quad * 4;
    #pragma unroll
    for (int j = 0; j < AJ; j++) {
      const int c = col0 + wn * WN + j * 16 + lr;
      #pragma unroll
      for (int r = 0; r < 4; r++) {
        float v = acc[i][j][r] * scale;
        if (HAS_BIAS) v += bb[j];
        if constexpr (sizeof(OutT) == 2)
          ((short*)C)[(size_t)(r0 + r) * ldc + c] = f2b(v);
        else
          ((float*)C)[(size_t)(r0 + r) * ldc + c] = v;
      }
    }
  }
}

// ---------------------------------------------------------------------------
// fp32 -> bf16 conversion for x, Wq, Wk, Wv (one launch). Unit = 8 floats.
// ---------------------------------------------------------------------------
#define XU  (N_TOK * DDIM / 8)      // 524288
#define WU  (DDIM * DDIM / 8)       // 131072
__global__ __launch_bounds__(256)
void cvt_all(const float* __restrict__ x,  const float* __restrict__ wq,
             const float* __restrict__ wk, const float* __restrict__ wv,
             short* __restrict__ xb, short* __restrict__ wqb,
             short* __restrict__ wkb, short* __restrict__ wvb)
{
  int gid = blockIdx.x * 256 + threadIdx.x;
  const float* src; short* dst; int off;
  if (gid < XU)               { src = x;  dst = xb;  off = gid; }
  else if (gid < XU + WU)     { src = wq; dst = wqb; off = gid - XU; }
  else if (gid < XU + 2 * WU) { src = wk; dst = wkb; off = gid - XU - WU; }
  else                        { src = wv; dst = wvb; off = gid - XU - 2 * WU; }
  const float4* g = reinterpret_cast<const float4*>(src) + (size_t)off * 2;
  float4 a = g[0], b = g[1];
  s16x8 o;
  o[0] = f2b(a.x); o[1] = f2b(a.y); o[2] = f2b(a.z); o[3] = f2b(a.w);
  o[4] = f2b(b.x); o[5] = f2b(b.y); o[6] = f2b(b.z); o[7] = f2b(b.w);
  reinterpret_cast<s16x8*>(dst)[off] = o;
}

// ---------------------------------------------------------------------------
// GEMM kernels
// ---------------------------------------------------------------------------
__global__ __launch_bounds__(256)
void k_qkv(const short* __restrict__ xb,
           const short* __restrict__ Wqb, const short* __restrict__ Wkb,
           const short* __restrict__ Wvb,
           const float* __restrict__ bq, const float* __restrict__ bk,
           const float* __restrict__ bv,
           short* __restrict__ Qb, short* __restrict__ Kb, short* __restrict__ Vb)
{
  const short* W; const float* bias; short* out;
  if (blockIdx.z == 0)      { W = Wqb; bias = bq; out = Qb; }
  else if (blockIdx.z == 1) { W = Wkb; bias = bk; out = Kb; }
  else                      { W = Wvb; bias = bv; out = Vb; }
  gemm_core<128, 128, short, true>(xb, W, out, bias, DDIM, DDIM, 1.0f,
                                   blockIdx.y * 128, blockIdx.x * 128);
}

__global__ __launch_bounds__(256)
void k_score(const short* __restrict__ Qb, const short* __restrict__ Kb,
             short* __restrict__ SP)
{
  gemm_core<128, 128, short, false>(Qb, Kb, SP, nullptr, DDIM, N_TOK, 0.03125f,
                                    blockIdx.y * 128, blockIdx.x * 128);
}

__global__ __launch_bounds__(256)
void k_pv(const short* __restrict__ SP, const short* __restrict__ Vt,
          float* __restrict__ out)
{
  gemm_core<128, 64, float, false>(SP, Vt, out, nullptr, N_TOK, DDIM, 1.0f,
                                   blockIdx.y * 128, blockIdx.x * 64);
}

// ---------------------------------------------------------------------------
// V [4096,1024] -> Vt [1024,4096] (bf16)
// ---------------------------------------------------------------------------
__global__ __launch_bounds__(256)
void transpose_bf16(const short* __restrict__ in, short* __restrict__ out)
{
  __shared__ short t[64][65];
  const int j0 = blockIdx.x * 64;
  const int i0 = blockIdx.y * 64;
  const int tid = threadIdx.x;
  const int r = tid >> 2;
  const int c = (tid & 3) * 16;

  const s16x8* g = reinterpret_cast<const s16x8*>(in + (size_t)(i0 + r) * DDIM + j0 + c);
  s16x8 v0 = g[0], v1 = g[1];
  #pragma unroll
  for (int k = 0; k < 8; k++) { t[r][c + k] = v0[k]; t[r][c + 8 + k] = v1[k]; }
  __syncthreads();

  s16x8 w0, w1;
  #pragma unroll
  for (int k = 0; k < 8; k++) { w0[k] = t[c + k][r]; w1[k] = t[c + 8 + k][r]; }
  s16x8* go = reinterpret_cast<s16x8*>(out + (size_t)(j0 + r) * N_TOK + i0 + c);
  go[0] = w0; go[1] = w1;
}

// ---------------------------------------------------------------------------
// In-place row softmax over bf16 [4096, 4096]
// ---------------------------------------------------------------------------
__global__ __launch_bounds__(256)
void softmax_rows(short* __restrict__ SP)
{
  const int row = blockIdx.x;
  short* p = SP + (size_t)row * N_TOK;
  const int tid = threadIdx.x;
  const int wid = tid >> 6, lane = tid & 63;

  float v[16];
  const s16x8* g = reinterpret_cast<const s16x8*>(p + tid * 16);
  s16x8 a0 = g[0], a1 = g[1];
  #pragma unroll
  for (int k = 0; k < 8; k++) { v[k] = b2f(a0[k]); v[8 + k] = b2f(a1[k]); }

  float m = -1e30f;
  #pragma unroll
  for (int k = 0; k < 16; k++) m = fmaxf(m, v[k]);
  #pragma unroll
  for (int off = 32; off > 0; off >>= 1) m = fmaxf(m, __shfl_xor(m, off, 64));

  __shared__ float redm[4], reds[4];
  if (lane == 0) redm[wid] = m;
  __syncthreads();
  m = fmaxf(fmaxf(redm[0], redm[1]), fmaxf(redm[2], redm[3]));

  float s = 0.f;
  #pragma unroll
  for (int k = 0; k < 16; k++) { v[k] = __expf(v[k] - m); s += v[k]; }
  #pragma unroll
  for (int off = 32; off > 0; off >>= 1) s += __shfl_xor(s, off, 64);
  if (lane == 0) reds[wid] = s;
  __syncthreads();
  s = reds[0] + reds[1] + reds[2] + reds[3];
  const float inv = 1.0f / s;

  s16x8 o0, o1;
  #pragma unroll
  for (int k = 0; k < 8; k++) { o0[k] = f2b(v[k] * inv); o1[k] = f2b(v[8 + k] * inv); }
  s16x8* go = reinterpret_cast<s16x8*>(p + tid * 16);
  go[0] = o0; go[1] = o1;
}

// ---------------------------------------------------------------------------
extern "C" void kernel_launch(void* const* d_in, const int* in_sizes, int n_in,
                              void* d_out, int out_size, void* d_ws, size_t ws_size,
                              hipStream_t stream)
{
  const float* x  = (const float*)d_in[0];
  const float* Wq = (const float*)d_in[1];
  const float* bq = (const float*)d_in[2];
  const float* Wk = (const float*)d_in[3];
  const float* bk = (const float*)d_in[4];
  const float* Wv = (const float*)d_in[5];
  const float* bv = (const float*)d_in[6];
  float* out = (float*)d_out;

  char* ws = (char*)d_ws;
  const size_t MB = 1024 * 1024;
  short* Qb  = (short*)(ws + 0 * MB);
  short* Kb  = (short*)(ws + 8 * MB);
  short* Vb  = (short*)(ws + 16 * MB);
  short* Vt  = (short*)(ws + 24 * MB);
  short* SP  = (short*)(ws + 32 * MB);   // 32 MB, live from k_score onward
  short* xb  = (short*)(ws + 32 * MB);   // overlaps SP (dead before k_score)
  short* Wqb = (short*)(ws + 40 * MB);
  short* Wkb = (short*)(ws + 42 * MB);
  short* Wvb = (short*)(ws + 44 * MB);

  dim3 b256(256);

  // fp32 -> bf16 for x and the three W's
  cvt_all<<<dim3((XU + 3 * WU) / 256), b256, 0, stream>>>(
      x, Wq, Wk, Wv, xb, Wqb, Wkb, Wvb);

  // Q/K/V = x @ W^T + b   (bf16 out), batched over z
  k_qkv<<<dim3(DDIM / 128, N_TOK / 128, 3), b256, 0, stream>>>(
      xb, Wqb, Wkb, Wvb, bq, bk, bv, Qb, Kb, Vb);

  // Vt = V^T
  transpose_bf16<<<dim3(DDIM / 64, N_TOK / 64), b256, 0, stream>>>(Vb, Vt);

  // S = Q @ K^T / 32  (bf16, overwrites xb region start? no: SP=xb region but xb dead now)
  k_score<<<dim3(N_TOK / 128, N_TOK / 128), b256, 0, stream>>>(Qb, Kb, SP);

  // P = softmax(S) in place
  softmax_rows<<<dim3(N_TOK), b256, 0, stream>>>(SP);

  // O = P @ Vt^T  (fp32 out), 128x64 tiles -> 512 blocks (2/CU)
  k_pv<<<dim3(DDIM / 64, N_TOK / 128), b256, 0, stream>>>(SP, Vt, out);
}